// Round 1
// baseline (134.185 us; speedup 1.0000x reference)
//
#include <hip/hip_runtime.h>
#include <math.h>

#define MDIM 1024
#define QTOT 65536
#define KTOP 16
#define NRBF 32
#define ODIM 256
#define FDIM 512

typedef float f32x4 __attribute__((ext_vector_type(4)));
typedef short s16x8 __attribute__((ext_vector_type(8)));

__device__ __forceinline__ short f2bf(float x) {
  unsigned u = __float_as_uint(x);
  u += 0x7FFFu + ((u >> 16) & 1u);   // RTNE
  return (short)(u >> 16);
}

__device__ __forceinline__ int read_mask(const void* m, int i, bool is8) {
  return is8 ? (int)((const unsigned char*)m)[i] : ((const int*)m)[i];
}

// ---------------- kernel 1: top-16 neighbor distances ----------------
// grid: QTOT/128 blocks x 256 threads. Block handles 128 queries of one batch.
__global__ __launch_bounds__(256) void topk_kernel(
    const float* __restrict__ coords, const void* __restrict__ mask,
    float* __restrict__ dists)
{
  __shared__ float4 pts[MDIM];
  __shared__ int s_cnt;
  __shared__ int s_is8;
  const int tid = threadIdx.x;
  const int lane = tid & 63;
  const int bid = blockIdx.x;
  const int batch = bid >> 3;      // 8 blocks per batch
  const int qchunk = bid & 7;

  if (tid == 0) { s_cnt = 0; s_is8 = 0; }
  __syncthreads();
  { // mask dtype detection: int32 0/1 words vs packed int8 bools
    unsigned w = ((const unsigned*)mask)[tid & 255];
    if (w > 1u) atomicOr(&s_is8, 1);
  }
  __syncthreads();
  const bool is8 = (s_is8 != 0);

  const float* cb = coords + (size_t)batch * MDIM * 3;
  const int mbase = batch * MDIM;

  // compact valid atoms into LDS: (x,y,z, idx-as-float)
  for (int r = 0; r < 4; ++r) {
    int a = r * 256 + tid;
    int v = read_mask(mask, mbase + a, is8);
    float x = cb[a*3+0], y = cb[a*3+1], z = cb[a*3+2];
    unsigned long long bal = __ballot(v != 0);
    int base = 0;
    if (lane == 0) base = atomicAdd(&s_cnt, __popcll(bal));
    base = __shfl(base, 0);
    int pos = __popcll(bal & ((1ull << lane) - 1ull));
    if (v) {
      float4 p; p.x = x; p.y = y; p.z = z; p.w = __int_as_float(a);
      pts[base + pos] = p;
    }
  }
  __syncthreads();
  const int cnt = s_cnt;

  // two lanes per query: lane l scans [0,h1), lane l^32 scans [h1,cnt)
  const int wv = tid >> 6;
  const int qlocal = qchunk * 128 + wv * 32 + (lane & 31);
  const float qx = cb[qlocal*3+0], qy = cb[qlocal*3+1], qz = cb[qlocal*3+2];
  const int half = lane >> 5;
  const int h1 = (cnt + 1) >> 1;
  const int lo = half ? h1 : 0;
  const int hi = half ? cnt : h1;

  float t[16];
  #pragma unroll
  for (int i = 0; i < 16; ++i) t[i] = 3.0e38f;

  for (int j = lo; j < hi; ++j) {
    float4 p = pts[j];
    float dx = p.x - qx, dy = p.y - qy, dz = p.z - qz;
    float d2 = fmaf(dx, dx, fmaf(dy, dy, dz * dz));
    int idx = __float_as_int(p.w);
    float d2m = (idx == qlocal) ? 3.0e38f : d2;   // exclude self
    if (__any(d2m < t[15])) {
      // parallel sorted-insert: 16 independent compare-exchanges
      float nt[16];
      nt[0] = fminf(t[0], d2m);
      #pragma unroll
      for (int k = 1; k < 16; ++k)
        nt[k] = fminf(t[k], fmaxf(t[k-1], d2m));
      #pragma unroll
      for (int k = 0; k < 16; ++k) t[k] = nt[k];
    }
  }

  // merge the two halves: bitonic
  float o_[16], m[16];
  #pragma unroll
  for (int i = 0; i < 16; ++i) o_[i] = __shfl(t[i], lane ^ 32);
  #pragma unroll
  for (int i = 0; i < 16; ++i) m[i] = fminf(t[i], o_[15 - i]);  // bitonic, 16 smallest
  #define CE(i,j) { float a_ = fminf(m[i], m[j]); float b_ = fmaxf(m[i], m[j]); m[i] = a_; m[j] = b_; }
  CE(0,8) CE(1,9) CE(2,10) CE(3,11) CE(4,12) CE(5,13) CE(6,14) CE(7,15)
  CE(0,4) CE(1,5) CE(2,6)  CE(3,7)  CE(8,12) CE(9,13) CE(10,14) CE(11,15)
  CE(0,2) CE(1,3) CE(4,6)  CE(5,7)  CE(8,10) CE(9,11) CE(12,14) CE(13,15)
  CE(0,1) CE(2,3) CE(4,5)  CE(6,7)  CE(8,9)  CE(10,11) CE(12,13) CE(14,15)
  #undef CE

  if (!(lane & 32)) {
    int mq = read_mask(mask, mbase + qlocal, is8);
    float res[16];
    #pragma unroll
    for (int i = 0; i < 16; ++i) {
      float v = m[i];
      float d = (v > 1.0e37f) ? 24.0f : sqrtf(fmaxf(v, 1e-12f)); // pad inf -> MAX_DIST
      res[i] = mq ? d : -1.0f;   // -1 sentinel => output row forced to zero
    }
    float4* dst = (float4*)(dists + (size_t)(mbase + qlocal) * KTOP);
    float4 o0, o1, o2, o3;
    o0.x=res[0];  o0.y=res[1];  o0.z=res[2];  o0.w=res[3];
    o1.x=res[4];  o1.y=res[5];  o1.z=res[6];  o1.w=res[7];
    o2.x=res[8];  o2.y=res[9];  o2.z=res[10]; o2.w=res[11];
    o3.x=res[12]; o3.y=res[13]; o3.z=res[14]; o3.w=res[15];
    dst[0]=o0; dst[1]=o1; dst[2]=o2; dst[3]=o3;
  }
}

// ---------------- kernel 2: fused RBF + projection (bf16 MFMA) ----------------
// grid: (4 n-blocks, QTOT/512 m-blocks) x 256 threads (4 waves).
// Wave owns 16 output cols; its full B panel (W^T bf16) lives in 64 VGPRs.
__global__ __launch_bounds__(256) void rbf_gemm_kernel(
    const float* __restrict__ dists, const float* __restrict__ W,
    float* __restrict__ out)
{
  const float SP = 24.0f / 31.0f;
  const float GAMMA_ = 1.0f / (SP * SP + 1e-8f);
  __shared__ __align__(16) short A_lds[32][520];   // bf16 bits, padded pitch

  const int tid = threadIdx.x;
  const int lane = tid & 63;
  const int wv = tid >> 6;
  const int nb = blockIdx.x;
  const int col = nb * 64 + wv * 16 + (lane & 15);
  const int ksub = (lane >> 4) * 8;

  // preload B fragments: B[k][n] = W[n][k]; lane reads its own W row, k-major
  s16x8 bfrag[16];
  const float* wr = W + (size_t)col * FDIM;
  #pragma unroll
  for (int s = 0; s < 16; ++s) {
    const float4* p = (const float4*)(wr + s * 32 + ksub);
    float4 w0 = p[0], w1 = p[1];
    s16x8 f;
    f[0]=f2bf(w0.x); f[1]=f2bf(w0.y); f[2]=f2bf(w0.z); f[3]=f2bf(w0.w);
    f[4]=f2bf(w1.x); f[5]=f2bf(w1.y); f[6]=f2bf(w1.z); f[7]=f2bf(w1.w);
    bfrag[s] = f;
  }

  const int qbase0 = blockIdx.y * 512;
  for (int mt = 0; mt < 16; ++mt) {
    const int qbase = qbase0 + mt * 32;

    // A-gen: 32 rows x 16 slots, 2 (row,slot) pairs per thread
    #pragma unroll
    for (int i = 0; i < 2; ++i) {
      int pidx = tid + 256 * i;
      int row = pidx >> 4, slot = pidx & 15;
      float d = dists[(size_t)(qbase + row) * KTOP + slot];
      d = (d < 0.f) ? 1.0e9f : d;        // sentinel -> rbf == 0 -> zero output row
      short* dstp = &A_lds[row][slot * 32];
      #pragma unroll
      for (int c8 = 0; c8 < 4; ++c8) {
        s16x8 v;
        #pragma unroll
        for (int j = 0; j < 8; ++j) {
          float diff = d - (float)(c8 * 8 + j) * SP;
          v[j] = f2bf(__expf(-GAMMA_ * diff * diff));
        }
        *(s16x8*)(dstp + c8 * 8) = v;
      }
    }
    __syncthreads();

    f32x4 acc0 = {0.f, 0.f, 0.f, 0.f};
    f32x4 acc1 = {0.f, 0.f, 0.f, 0.f};
    const short* ar0 = &A_lds[lane & 15][ksub];
    const short* ar1 = &A_lds[16 + (lane & 15)][ksub];
    #pragma unroll
    for (int s = 0; s < 16; ++s) {
      s16x8 a0 = *(const s16x8*)(ar0 + s * 32);
      s16x8 a1 = *(const s16x8*)(ar1 + s * 32);
      acc0 = __builtin_amdgcn_mfma_f32_16x16x32_bf16(a0, bfrag[s], acc0, 0, 0, 0);
      acc1 = __builtin_amdgcn_mfma_f32_16x16x32_bf16(a1, bfrag[s], acc1, 0, 0, 0);
    }
    __syncthreads();

    // C/D layout: col = lane&15, row = (lane>>4)*4 + reg  [m89-verified]
    const int rb = (lane >> 4) * 4;
    #pragma unroll
    for (int r = 0; r < 4; ++r) {
      out[(size_t)(qbase + rb + r) * ODIM + col]      = acc0[r];
      out[(size_t)(qbase + 16 + rb + r) * ODIM + col] = acc1[r];
    }
  }
}

extern "C" void kernel_launch(void* const* d_in, const int* in_sizes, int n_in,
                              void* d_out, int out_size, void* d_ws, size_t ws_size,
                              hipStream_t stream) {
  const float* coords = (const float*)d_in[0];
  const void* mask = d_in[1];
  const float* W = (const float*)d_in[2];
  float* out = (float*)d_out;
  float* dists = (float*)d_ws;   // QTOT * 16 fp32 = 4 MB scratch

  hipLaunchKernelGGL(topk_kernel, dim3(QTOT / 128), dim3(256), 0, stream,
                     coords, mask, dists);
  hipLaunchKernelGGL(rbf_gemm_kernel, dim3(4, QTOT / 512), dim3(256), 0, stream,
                     dists, W, out);
}

// Round 2
// 111.963 us; speedup vs baseline: 1.1985x; 1.1985x over previous
//
#include <hip/hip_runtime.h>
#include <math.h>

#define MDIM 1024
#define QTOT 65536
#define KTOP 16
#define ODIM 256
#define FDIM 512

typedef float f32x4 __attribute__((ext_vector_type(4)));
typedef short s16x8 __attribute__((ext_vector_type(8)));

__device__ __forceinline__ short f2bf(float x) {
  unsigned u = __float_as_uint(x);
  u += 0x7FFFu + ((u >> 16) & 1u);   // RTNE
  return (short)(u >> 16);
}

__device__ __forceinline__ int read_mask(const void* m, int i, bool is8) {
  return is8 ? (int)((const unsigned char*)m)[i] : ((const int*)m)[i];
}

__device__ __forceinline__ float min3f(float a, float b, float c) {
  return fminf(fminf(a, b), c);   // clang fuses to v_min3_f32
}

// ---------------- kernel 1: top-16 neighbor distances ----------------
// grid: QTOT/64 blocks x 256 threads. Block = 64 queries of one batch,
// 4 lanes per query (quarter-streams), unconditional paired insert.
__global__ __launch_bounds__(256) void topk_kernel(
    const float* __restrict__ coords, const void* __restrict__ mask,
    float* __restrict__ dists)
{
  __shared__ float4 pts[MDIM];
  __shared__ int s_cnt;
  __shared__ int s_is8;
  const int tid = threadIdx.x;
  const int lane = tid & 63;
  const int bid = blockIdx.x;
  const int batch = bid >> 4;      // 16 blocks per batch
  const int qchunk = bid & 15;

  if (tid == 0) { s_cnt = 0; s_is8 = 0; }
  __syncthreads();
  { // mask dtype detection: int32 0/1 words vs packed int8 bools
    unsigned w = ((const unsigned*)mask)[tid & 255];
    if (w > 1u) atomicOr(&s_is8, 1);
  }
  __syncthreads();
  const bool is8 = (s_is8 != 0);

  const float* cb = coords + (size_t)batch * MDIM * 3;
  const int mbase = batch * MDIM;

  // compact valid atoms into LDS: (x,y,z, idx-as-float)
  for (int r = 0; r < 4; ++r) {
    int a = r * 256 + tid;
    int v = read_mask(mask, mbase + a, is8);
    float x = cb[a*3+0], y = cb[a*3+1], z = cb[a*3+2];
    unsigned long long bal = __ballot(v != 0);
    int base = 0;
    if (lane == 0) base = atomicAdd(&s_cnt, __popcll(bal));
    base = __shfl(base, 0);
    int pos = __popcll(bal & ((1ull << lane) - 1ull));
    if (v) {
      float4 p; p.x = x; p.y = y; p.z = z; p.w = __int_as_float(a);
      pts[base + pos] = p;
    }
  }
  __syncthreads();
  const int cnt = s_cnt;

  // 4 lanes per query: lane = qi + 16*part; part scans its quarter-range
  const int wv = tid >> 6;
  const int qi = lane & 15;
  const int part = lane >> 4;
  const int qlocal = qchunk * 64 + wv * 16 + qi;
  const float qx = cb[qlocal*3+0], qy = cb[qlocal*3+1], qz = cb[qlocal*3+2];
  const int lo = (cnt * part) >> 2;
  const int hi = (cnt * (part + 1)) >> 2;

  float t[16];
  #pragma unroll
  for (int i = 0; i < 16; ++i) t[i] = 3.0e38f;

  int j = lo;
  for (; j + 2 <= hi; j += 2) {
    float4 p0 = pts[j];
    float4 p1 = pts[j + 1];
    float dx0 = p0.x - qx, dy0 = p0.y - qy, dz0 = p0.z - qz;
    float dx1 = p1.x - qx, dy1 = p1.y - qy, dz1 = p1.z - qz;
    float d0 = fmaf(dx0, dx0, fmaf(dy0, dy0, dz0 * dz0));
    float d1 = fmaf(dx1, dx1, fmaf(dy1, dy1, dz1 * dz1));
    if (__float_as_int(p0.w) == qlocal) d0 = 3.0e38f;   // exclude self
    if (__float_as_int(p1.w) == qlocal) d1 = 3.0e38f;
    float x = fminf(d0, d1), y = fmaxf(d0, d1);
    // insert sorted pair (x<=y), keep 16 smallest; in-place, downward
    #pragma unroll
    for (int k = 15; k >= 2; --k)
      t[k] = min3f(t[k], fmaxf(t[k-1], x), fmaxf(t[k-2], y));
    t[1] = min3f(t[1], fmaxf(t[0], x), y);
    t[0] = min3f(t[0], x, y);
  }
  if (j < hi) {   // trailing single
    float4 p0 = pts[j];
    float dx0 = p0.x - qx, dy0 = p0.y - qy, dz0 = p0.z - qz;
    float d0 = fmaf(dx0, dx0, fmaf(dy0, dy0, dz0 * dz0));
    if (__float_as_int(p0.w) == qlocal) d0 = 3.0e38f;
    #pragma unroll
    for (int k = 15; k >= 1; --k)
      t[k] = fminf(t[k], fmaxf(t[k-1], d0));
    t[0] = fminf(t[0], d0);
  }

  // merge the 4 quarter-lists: bitonic merge with partner ^16, then ^32
  #pragma unroll
  for (int stepi = 0; stepi < 2; ++stepi) {
    const int step = stepi == 0 ? 16 : 32;
    float o_[16], m[16];
    #pragma unroll
    for (int i = 0; i < 16; ++i) o_[i] = __shfl(t[i], lane ^ step);
    #pragma unroll
    for (int i = 0; i < 16; ++i) m[i] = fminf(t[i], o_[15 - i]);
    #define CE(i,jj) { float a_ = fminf(m[i], m[jj]); float b_ = fmaxf(m[i], m[jj]); m[i] = a_; m[jj] = b_; }
    CE(0,8) CE(1,9) CE(2,10) CE(3,11) CE(4,12) CE(5,13) CE(6,14) CE(7,15)
    CE(0,4) CE(1,5) CE(2,6)  CE(3,7)  CE(8,12) CE(9,13) CE(10,14) CE(11,15)
    CE(0,2) CE(1,3) CE(4,6)  CE(5,7)  CE(8,10) CE(9,11) CE(12,14) CE(13,15)
    CE(0,1) CE(2,3) CE(4,5)  CE(6,7)  CE(8,9)  CE(10,11) CE(12,13) CE(14,15)
    #undef CE
    #pragma unroll
    for (int i = 0; i < 16; ++i) t[i] = m[i];
  }

  if (part == 0) {
    int mq = read_mask(mask, mbase + qlocal, is8);
    float res[16];
    #pragma unroll
    for (int i = 0; i < 16; ++i) {
      float v = t[i];
      float d = (v > 1.0e37f) ? 24.0f : sqrtf(fmaxf(v, 1e-12f)); // pad inf -> MAX_DIST
      res[i] = mq ? d : -1.0f;   // -1 sentinel => output row forced to zero
    }
    float4* dst = (float4*)(dists + (size_t)(mbase + qlocal) * KTOP);
    float4 o0, o1, o2, o3;
    o0.x=res[0];  o0.y=res[1];  o0.z=res[2];  o0.w=res[3];
    o1.x=res[4];  o1.y=res[5];  o1.z=res[6];  o1.w=res[7];
    o2.x=res[8];  o2.y=res[9];  o2.z=res[10]; o2.w=res[11];
    o3.x=res[12]; o3.y=res[13]; o3.z=res[14]; o3.w=res[15];
    dst[0]=o0; dst[1]=o1; dst[2]=o2; dst[3]=o3;
  }
}

// ---------------- kernel 2: fused RBF + projection (bf16 MFMA) ----------------
// grid: (4 n-blocks, QTOT/128 m-blocks) x 256 threads (4 waves).
// Wave owns 16 output cols; full B panel (W^T bf16) in 64 VGPRs.
// 4 row-tiles of 32 per block; dists for all tiles preloaded to registers.
__global__ __launch_bounds__(256) void rbf_gemm_kernel(
    const float* __restrict__ dists, const float* __restrict__ W,
    float* __restrict__ out)
{
  const float SP = 24.0f / 31.0f;
  const float GAMMA_ = 1.0f / (SP * SP + 1e-8f);
  __shared__ __align__(16) short A_lds[32][520];   // bf16 bits, padded pitch

  const int tid = threadIdx.x;
  const int lane = tid & 63;
  const int wv = tid >> 6;
  const int nb = blockIdx.x;
  const int col = nb * 64 + wv * 16 + (lane & 15);
  const int ksub = (lane >> 4) * 8;

  // preload B fragments: B[k][n] = W[n][k]; lane reads its own W row, k-major
  s16x8 bfrag[16];
  const float* wr = W + (size_t)col * FDIM;
  #pragma unroll
  for (int s = 0; s < 16; ++s) {
    const float4* p = (const float4*)(wr + s * 32 + ksub);
    float4 w0 = p[0], w1 = p[1];
    s16x8 f;
    f[0]=f2bf(w0.x); f[1]=f2bf(w0.y); f[2]=f2bf(w0.z); f[3]=f2bf(w0.w);
    f[4]=f2bf(w1.x); f[5]=f2bf(w1.y); f[6]=f2bf(w1.z); f[7]=f2bf(w1.w);
    bfrag[s] = f;
  }

  const int qbase0 = blockIdx.y * 128;
  const int row0 = tid >> 4, slot = tid & 15;   // this thread's A-gen cell

  // preload all 4 tiles' distances (coalesced: consecutive tid = consecutive addr)
  float dv[4][2];
  #pragma unroll
  for (int t4 = 0; t4 < 4; ++t4)
    #pragma unroll
    for (int i = 0; i < 2; ++i)
      dv[t4][i] = dists[(size_t)(qbase0 + t4 * 32 + i * 16 + row0) * KTOP + slot];

  #pragma unroll
  for (int t4 = 0; t4 < 4; ++t4) {
    const int qbase = qbase0 + t4 * 32;

    // A-gen: thread fills rows {row0, row0+16}, its slot (32 bf16 each)
    #pragma unroll
    for (int i = 0; i < 2; ++i) {
      float d = dv[t4][i];
      d = (d < 0.f) ? 1.0e9f : d;        // sentinel -> rbf == 0 -> zero output row
      short* dstp = &A_lds[i * 16 + row0][slot * 32];
      #pragma unroll
      for (int c8 = 0; c8 < 4; ++c8) {
        s16x8 v;
        #pragma unroll
        for (int jj = 0; jj < 8; ++jj) {
          float diff = d - (float)(c8 * 8 + jj) * SP;
          v[jj] = f2bf(__expf(-GAMMA_ * diff * diff));
        }
        *(s16x8*)(dstp + c8 * 8) = v;
      }
    }
    __syncthreads();

    f32x4 acc0 = {0.f, 0.f, 0.f, 0.f};
    f32x4 acc1 = {0.f, 0.f, 0.f, 0.f};
    const short* ar0 = &A_lds[lane & 15][ksub];
    const short* ar1 = &A_lds[16 + (lane & 15)][ksub];
    #pragma unroll
    for (int s = 0; s < 16; ++s) {
      s16x8 a0 = *(const s16x8*)(ar0 + s * 32);
      s16x8 a1 = *(const s16x8*)(ar1 + s * 32);
      acc0 = __builtin_amdgcn_mfma_f32_16x16x32_bf16(a0, bfrag[s], acc0, 0, 0, 0);
      acc1 = __builtin_amdgcn_mfma_f32_16x16x32_bf16(a1, bfrag[s], acc1, 0, 0, 0);
    }
    __syncthreads();

    // C/D layout: col = lane&15, row = (lane>>4)*4 + reg
    const int rb = (lane >> 4) * 4;
    #pragma unroll
    for (int r = 0; r < 4; ++r) {
      out[(size_t)(qbase + rb + r) * ODIM + col]      = acc0[r];
      out[(size_t)(qbase + 16 + rb + r) * ODIM + col] = acc1[r];
    }
  }
}

extern "C" void kernel_launch(void* const* d_in, const int* in_sizes, int n_in,
                              void* d_out, int out_size, void* d_ws, size_t ws_size,
                              hipStream_t stream) {
  const float* coords = (const float*)d_in[0];
  const void* mask = d_in[1];
  const float* W = (const float*)d_in[2];
  float* out = (float*)d_out;
  float* dists = (float*)d_ws;   // QTOT * 16 fp32 = 4 MB scratch

  hipLaunchKernelGGL(topk_kernel, dim3(QTOT / 64), dim3(256), 0, stream,
                     coords, mask, dists);
  hipLaunchKernelGGL(rbf_gemm_kernel, dim3(4, QTOT / 128), dim3(256), 0, stream,
                     dists, W, out);
}

// Round 4
// 87.862 us; speedup vs baseline: 1.5272x; 1.2743x over previous
//
#include <hip/hip_runtime.h>
#include <hip/hip_bf16.h>
#include <math.h>

#define MDIM 1024
#define QTOT 65536
#define KTOP 16
#define ODIM 256
#define FDIM 512
#define TTILES 8

typedef float f32x4 __attribute__((ext_vector_type(4)));
typedef short s16x8 __attribute__((ext_vector_type(8)));
typedef unsigned u32x4 __attribute__((ext_vector_type(4)));

#if __has_builtin(__builtin_amdgcn_exp2f)
#define EXP2(x) __builtin_amdgcn_exp2f(x)
#else
#define EXP2(x) exp2f(x)
#endif

__device__ __forceinline__ int read_mask(const void* m, int i, bool is8) {
  return is8 ? (int)((const unsigned char*)m)[i] : ((const int*)m)[i];
}

__device__ __forceinline__ float min3f(float a, float b, float c) {
  return fminf(fminf(a, b), c);   // fuses to v_min3_f32
}

__device__ __forceinline__ unsigned pack2(float lo, float hi) {
  __hip_bfloat162 h = __float22bfloat162_rn(make_float2(lo, hi));
  unsigned u;
  __builtin_memcpy(&u, &h, sizeof(u));
  return u;
}

// ---------------- kernel 1: top-16 neighbor distances ----------------
// grid: QTOT/64 blocks x 512 threads. Block = 64 queries of one batch,
// 8 lanes per query. Distances tracked in (d^2 - |q|^2) space: 3 fma each.
__global__ __launch_bounds__(512, 4) void topk_kernel(
    const float* __restrict__ coords, const void* __restrict__ mask,
    float* __restrict__ dists)
{
  __shared__ float4 pts[MDIM];   // (x, y, z, |p|^2)
  __shared__ int posof[MDIM];    // atom -> compacted position (-1 if masked)
  __shared__ int s_cnt;
  __shared__ int s_is8;
  const int tid = threadIdx.x;
  const int lane = tid & 63;
  const int wv = tid >> 6;
  const int bid = blockIdx.x;
  const int batch = bid >> 4;      // 16 blocks per batch
  const int qchunk = bid & 15;

  if (tid == 0) { s_cnt = 0; s_is8 = 0; }
  __syncthreads();
  { // mask dtype detection: int32 0/1 words vs packed int8 bools
    unsigned w = ((const unsigned*)mask)[tid & 255];
    if (w > 1u) atomicOr(&s_is8, 1);
  }
  __syncthreads();
  const bool is8 = (s_is8 != 0);

  const float* cb = coords + (size_t)batch * MDIM * 3;
  const int mbase = batch * MDIM;

  // compact valid atoms into LDS
  #pragma unroll
  for (int r = 0; r < 2; ++r) {
    int a = r * 512 + tid;
    int v = read_mask(mask, mbase + a, is8);
    float x = cb[a*3+0], y = cb[a*3+1], z = cb[a*3+2];
    float S = fmaf(z, z, fmaf(y, y, x * x));
    unsigned long long bal = __ballot(v != 0);
    int base = 0;
    if (lane == 0) base = atomicAdd(&s_cnt, __popcll(bal));
    base = __shfl(base, 0);
    int pos = base + __popcll(bal & ((1ull << lane) - 1ull));
    if (v) {
      float4 p; p.x = x; p.y = y; p.z = z; p.w = S;
      pts[pos] = p;
    }
    posof[a] = v ? pos : -1;
  }
  __syncthreads();
  const int cnt = s_cnt;

  // 8 lanes per query: lane = qi + 8*part
  const int qi = lane & 7;
  const int part = lane >> 3;
  const int qlocal = qchunk * 64 + wv * 8 + qi;
  const float qx = cb[qlocal*3+0], qy = cb[qlocal*3+1], qz = cb[qlocal*3+2];
  const float Q = fmaf(qz, qz, fmaf(qy, qy, qx * qx));
  const float m2x = -2.0f * qx, m2y = -2.0f * qy, m2z = -2.0f * qz;
  const int selfpos = posof[qlocal];
  const int lo = (cnt * part) >> 3;
  const int hi = (cnt * (part + 1)) >> 3;

  float t[16];
  #pragma unroll
  for (int i = 0; i < 16; ++i) t[i] = 3.0e38f;

  int j = lo;
  for (; j + 2 <= hi; j += 2) {
    float4 p0 = pts[j];
    float4 p1 = pts[j + 1];
    // d' = |p|^2 - 2 q.p  (= d^2 - Q, order-preserving)
    float d0 = fmaf(p0.z, m2z, fmaf(p0.y, m2y, fmaf(p0.x, m2x, p0.w)));
    float d1 = fmaf(p1.z, m2z, fmaf(p1.y, m2y, fmaf(p1.x, m2x, p1.w)));
    if (j == selfpos)     d0 = 3.0e38f;
    if (j + 1 == selfpos) d1 = 3.0e38f;
    float x = fminf(d0, d1), y = fmaxf(d0, d1);
    #pragma unroll
    for (int k = 15; k >= 2; --k)
      t[k] = min3f(t[k], fmaxf(t[k-1], x), fmaxf(t[k-2], y));
    t[1] = min3f(t[1], fmaxf(t[0], x), y);
    t[0] = min3f(t[0], x, y);
  }
  if (j < hi) {   // trailing single
    float4 p0 = pts[j];
    float d0 = fmaf(p0.z, m2z, fmaf(p0.y, m2y, fmaf(p0.x, m2x, p0.w)));
    if (j == selfpos) d0 = 3.0e38f;
    #pragma unroll
    for (int k = 15; k >= 1; --k)
      t[k] = fminf(t[k], fmaxf(t[k-1], d0));
    t[0] = fminf(t[0], d0);
  }

  // merge the 8 part-lists: bitonic merges with partners ^8, ^16, ^32
  #pragma unroll
  for (int stepi = 0; stepi < 3; ++stepi) {
    const int step = 8 << stepi;
    float o_[16], m[16];
    #pragma unroll
    for (int i = 0; i < 16; ++i) o_[i] = __shfl(t[i], lane ^ step);
    #pragma unroll
    for (int i = 0; i < 16; ++i) m[i] = fminf(t[i], o_[15 - i]);
    #define CE(i,jj) { float a_ = fminf(m[i], m[jj]); float b_ = fmaxf(m[i], m[jj]); m[i] = a_; m[jj] = b_; }
    CE(0,8) CE(1,9) CE(2,10) CE(3,11) CE(4,12) CE(5,13) CE(6,14) CE(7,15)
    CE(0,4) CE(1,5) CE(2,6)  CE(3,7)  CE(8,12) CE(9,13) CE(10,14) CE(11,15)
    CE(0,2) CE(1,3) CE(4,6)  CE(5,7)  CE(8,10) CE(9,11) CE(12,14) CE(13,15)
    CE(0,1) CE(2,3) CE(4,5)  CE(6,7)  CE(8,9)  CE(10,11) CE(12,13) CE(14,15)
    #undef CE
    #pragma unroll
    for (int i = 0; i < 16; ++i) t[i] = m[i];
  }

  if (part == 0) {
    int mq = read_mask(mask, mbase + qlocal, is8);
    float res[16];
    #pragma unroll
    for (int i = 0; i < 16; ++i) {
      float v = t[i];
      float d = (v > 1.0e37f) ? 24.0f : sqrtf(fmaxf(v + Q, 1e-12f)); // pad inf -> MAX_DIST
      res[i] = mq ? d : -1.0f;   // -1 sentinel => output row forced to zero
    }
    float4* dst = (float4*)(dists + (size_t)(mbase + qlocal) * KTOP);
    float4 o0, o1, o2, o3;
    o0.x=res[0];  o0.y=res[1];  o0.z=res[2];  o0.w=res[3];
    o1.x=res[4];  o1.y=res[5];  o1.z=res[6];  o1.w=res[7];
    o2.x=res[8];  o2.y=res[9];  o2.z=res[10]; o2.w=res[11];
    o3.x=res[12]; o3.y=res[13]; o3.z=res[14]; o3.w=res[15];
    dst[0]=o0; dst[1]=o1; dst[2]=o2; dst[3]=o3;
  }
}

// ---------------- kernel 2: fused RBF + projection (bf16 MFMA) ----------------
// grid: (2 n-blocks, QTOT/256 m-blocks) x 256 threads (4 waves).
// Wave owns 32 cols (2 B-sets, 128 VGPR). A staged in frag-major LDS layout
// (bank-balanced, lane-linear reads), double-buffered, 1 barrier/tile.
constexpr double SPd = 24.0 / 31.0;
constexpr double SP2d = SPd * SPd;
constexpr float ALPHA = (float)(-(SP2d / (SP2d + 1e-8)) * 1.4426950408889634);
constexpr float INV_SP = (float)(1.0 / SPd);

__device__ __forceinline__ void gen_tile(u32x4 (*Abuf)[1040], int row0, int s,
                                         float d0, float d1) {
  float dd0 = (d0 < 0.f) ? 1.0e9f : d0;   // sentinel -> rbf == 0
  float dd1 = (d1 < 0.f) ? 1.0e9f : d1;
  #pragma unroll
  for (int i = 0; i < 2; ++i) {
    float d = i ? dd1 : dd0;
    float u = d * INV_SP;
    float C1 = (-2.0f * ALPHA) * u;
    float C0 = ALPHA * u * u;
    #pragma unroll
    for (int c8 = 0; c8 < 4; ++c8) {
      u32x4 ch;
      #pragma unroll
      for (int q = 0; q < 4; ++q) {
        const int j0 = c8 * 8 + q * 2;
        float e0 = EXP2(fmaf(C1, (float)j0,       C0) + ALPHA * (float)(j0 * j0));
        float e1 = EXP2(fmaf(C1, (float)(j0 + 1), C0) + ALPHA * (float)((j0 + 1) * (j0 + 1)));
        ch[q] = pack2(e0, e1);
      }
      Abuf[i][s * 65 + c8 * 16 + row0] = ch;
    }
  }
}

__global__ __launch_bounds__(256, 2) void rbf_gemm_kernel(
    const float* __restrict__ dists, const float* __restrict__ W,
    float* __restrict__ out)
{
  __shared__ u32x4 A_sh[2][2][1040];   // [buf][row-half][s*65 + fragslot]

  const int tid = threadIdx.x;
  const int lane = tid & 63;
  const int wv = tid >> 6;
  const int c0 = blockIdx.x * 128 + wv * 32 + (lane & 15);
  const int ksub = (lane >> 4) * 8;

  // preload B fragments for 2 col-sets: B[k][n] = W[n][k]
  s16x8 bf0[16], bf1[16];
  const float* wr0 = W + (size_t)c0 * FDIM;
  const float* wr1 = wr0 + (size_t)16 * FDIM;
  #pragma unroll
  for (int s = 0; s < 16; ++s) {
    const float4* p0 = (const float4*)(wr0 + s * 32 + ksub);
    const float4* p1 = (const float4*)(wr1 + s * 32 + ksub);
    float4 a = p0[0], b = p0[1], c = p1[0], d = p1[1];
    u32x4 u0, u1;
    u0[0] = pack2(a.x, a.y); u0[1] = pack2(a.z, a.w);
    u0[2] = pack2(b.x, b.y); u0[3] = pack2(b.z, b.w);
    u1[0] = pack2(c.x, c.y); u1[1] = pack2(c.z, c.w);
    u1[2] = pack2(d.x, d.y); u1[3] = pack2(d.z, d.w);
    __builtin_memcpy(&bf0[s], &u0, sizeof(u0));
    __builtin_memcpy(&bf1[s], &u1, sizeof(u1));
  }

  const int row0 = tid >> 4;       // gen cell: row (and row+16), slot
  const int sgen = tid & 15;
  const int qbase0 = blockIdx.y * (32 * TTILES);
  const size_t dbase = (size_t)qbase0 * KTOP;

  float p0 = dists[dbase + tid];
  float p1 = dists[dbase + 256 + tid];
  gen_tile(A_sh[0], row0, sgen, p0, p1);

  for (int t = 0; t < TTILES; ++t) {
    float n0 = 0.f, n1 = 0.f;
    if (t + 1 < TTILES) {
      n0 = dists[dbase + (size_t)(t + 1) * 512 + tid];
      n1 = dists[dbase + (size_t)(t + 1) * 512 + 256 + tid];
    }
    __syncthreads();
    if (t + 1 < TTILES) gen_tile(A_sh[(t + 1) & 1], row0, sgen, n0, n1);

    const int buf = t & 1;
    f32x4 acc00 = {0.f,0.f,0.f,0.f}, acc01 = {0.f,0.f,0.f,0.f};
    f32x4 acc10 = {0.f,0.f,0.f,0.f}, acc11 = {0.f,0.f,0.f,0.f};
    #pragma unroll
    for (int s = 0; s < 16; ++s) {
      s16x8 a0, a1;
      u32x4 ra0 = A_sh[buf][0][s * 65 + lane];
      u32x4 ra1 = A_sh[buf][1][s * 65 + lane];
      __builtin_memcpy(&a0, &ra0, sizeof(ra0));
      __builtin_memcpy(&a1, &ra1, sizeof(ra1));
      acc00 = __builtin_amdgcn_mfma_f32_16x16x32_bf16(a0, bf0[s], acc00, 0, 0, 0);
      acc01 = __builtin_amdgcn_mfma_f32_16x16x32_bf16(a0, bf1[s], acc01, 0, 0, 0);
      acc10 = __builtin_amdgcn_mfma_f32_16x16x32_bf16(a1, bf0[s], acc10, 0, 0, 0);
      acc11 = __builtin_amdgcn_mfma_f32_16x16x32_bf16(a1, bf1[s], acc11, 0, 0, 0);
    }

    const int qbase = qbase0 + t * 32;
    const int rb = (lane >> 4) * 4;
    #pragma unroll
    for (int r = 0; r < 4; ++r) {
      __builtin_nontemporal_store(acc00[r], out + (size_t)(qbase + rb + r) * ODIM + c0);
      __builtin_nontemporal_store(acc01[r], out + (size_t)(qbase + rb + r) * ODIM + c0 + 16);
      __builtin_nontemporal_store(acc10[r], out + (size_t)(qbase + 16 + rb + r) * ODIM + c0);
      __builtin_nontemporal_store(acc11[r], out + (size_t)(qbase + 16 + rb + r) * ODIM + c0 + 16);
    }
  }
}

extern "C" void kernel_launch(void* const* d_in, const int* in_sizes, int n_in,
                              void* d_out, int out_size, void* d_ws, size_t ws_size,
                              hipStream_t stream) {
  const float* coords = (const float*)d_in[0];
  const void* mask = d_in[1];
  const float* W = (const float*)d_in[2];
  float* out = (float*)d_out;
  float* dists = (float*)d_ws;   // QTOT * 16 fp32 = 4 MB scratch

  hipLaunchKernelGGL(topk_kernel, dim3(QTOT / 64), dim3(512), 0, stream,
                     coords, mask, dists);
  hipLaunchKernelGGL(rbf_gemm_kernel, dim3(2, QTOT / (32 * TTILES)), dim3(256), 0, stream,
                     dists, W, out);
}

// Round 5
// 80.325 us; speedup vs baseline: 1.6705x; 1.0938x over previous
//
#include <hip/hip_runtime.h>
#include <hip/hip_bf16.h>
#include <math.h>

#define MDIM 1024
#define QTOT 65536
#define KTOP 16
#define ODIM 256
#define FDIM 512
#define TTILES 8

typedef float f32x4 __attribute__((ext_vector_type(4)));
typedef short s16x8 __attribute__((ext_vector_type(8)));
typedef unsigned u32x4 __attribute__((ext_vector_type(4)));

#if __has_builtin(__builtin_amdgcn_exp2f)
#define EXP2(x) __builtin_amdgcn_exp2f(x)
#else
#define EXP2(x) exp2f(x)
#endif

// pinned single-instruction min/max (avoid minnum/maxnum canonicalization bloat)
#define VMIN(a,b)    ({float r_; asm("v_min_f32 %0,%1,%2":"=v"(r_):"v"(a),"v"(b)); r_;})
#define VMAX(a,b)    ({float r_; asm("v_max_f32 %0,%1,%2":"=v"(r_):"v"(a),"v"(b)); r_;})
#define VMIN3(a,b,c) ({float r_; asm("v_min3_f32 %0,%1,%2,%3":"=v"(r_):"v"(a),"v"(b),"v"(c)); r_;})

__device__ __forceinline__ int read_mask(const void* m, int i, bool is8) {
  return is8 ? (int)((const unsigned char*)m)[i] : ((const int*)m)[i];
}

__device__ __forceinline__ unsigned pack2(float lo, float hi) {
  __hip_bfloat162 h = __float22bfloat162_rn(make_float2(lo, hi));
  unsigned u;
  __builtin_memcpy(&u, &h, sizeof(u));
  return u;
}

// ---------------- kernel 1: top-16 neighbor distances ----------------
// grid: QTOT/64 blocks x 512 threads. Block = 64 queries of one batch,
// 8 lanes per query. Distances tracked in (d^2 - |q|^2) space: 3 fma each.
__global__ __launch_bounds__(512, 4) void topk_kernel(
    const float* __restrict__ coords, const void* __restrict__ mask,
    float* __restrict__ dists)
{
  __shared__ float4 pts[MDIM];   // (x, y, z, |p|^2)
  __shared__ int posof[MDIM];    // atom -> compacted position (-1 if masked)
  __shared__ int s_cnt;
  __shared__ int s_is8;
  const int tid = threadIdx.x;
  const int lane = tid & 63;
  const int wv = tid >> 6;
  const int bid = blockIdx.x;
  const int batch = bid >> 4;      // 16 blocks per batch
  const int qchunk = bid & 15;

  if (tid == 0) { s_cnt = 0; s_is8 = 0; }
  __syncthreads();
  { // mask dtype detection: int32 0/1 words vs packed int8 bools
    unsigned w = ((const unsigned*)mask)[tid & 255];
    if (w > 1u) atomicOr(&s_is8, 1);
  }
  __syncthreads();
  const bool is8 = (s_is8 != 0);

  const float* cb = coords + (size_t)batch * MDIM * 3;
  const int mbase = batch * MDIM;

  // compact valid atoms into LDS
  #pragma unroll
  for (int r = 0; r < 2; ++r) {
    int a = r * 512 + tid;
    int v = read_mask(mask, mbase + a, is8);
    float x = cb[a*3+0], y = cb[a*3+1], z = cb[a*3+2];
    float S = fmaf(z, z, fmaf(y, y, x * x));
    unsigned long long bal = __ballot(v != 0);
    int base = 0;
    if (lane == 0) base = atomicAdd(&s_cnt, __popcll(bal));
    base = __shfl(base, 0);
    int pos = base + __popcll(bal & ((1ull << lane) - 1ull));
    if (v) {
      float4 p; p.x = x; p.y = y; p.z = z; p.w = S;
      pts[pos] = p;
    }
    posof[a] = v ? pos : -1;
  }
  __syncthreads();
  const int cnt = s_cnt;

  // 8 lanes per query: lane = qi + 8*part
  const int qi = lane & 7;
  const int part = lane >> 3;
  const int qlocal = qchunk * 64 + wv * 8 + qi;
  const float qx = cb[qlocal*3+0], qy = cb[qlocal*3+1], qz = cb[qlocal*3+2];
  const float Q = fmaf(qz, qz, fmaf(qy, qy, qx * qx));
  const float m2x = -2.0f * qx, m2y = -2.0f * qy, m2z = -2.0f * qz;
  const int selfpos = posof[qlocal];
  const int lo = (cnt * part) >> 3;
  const int hi = (cnt * (part + 1)) >> 3;

  float t[16];
  #pragma unroll
  for (int i = 0; i < 16; ++i) t[i] = 3.0e38f;

  int j = lo;
  for (; j + 2 <= hi; j += 2) {
    float4 p0 = pts[j];
    float4 p1 = pts[j + 1];
    // d' = |p|^2 - 2 q.p  (= d^2 - Q, order-preserving)
    float d0 = fmaf(p0.z, m2z, fmaf(p0.y, m2y, fmaf(p0.x, m2x, p0.w)));
    float d1 = fmaf(p1.z, m2z, fmaf(p1.y, m2y, fmaf(p1.x, m2x, p1.w)));
    if (j == selfpos)     d0 = 3.0e38f;
    if (j + 1 == selfpos) d1 = 3.0e38f;
    float x = VMIN(d0, d1), y = VMAX(d0, d1);
    #pragma unroll
    for (int k = 15; k >= 2; --k)
      t[k] = VMIN3(t[k], VMAX(t[k-1], x), VMAX(t[k-2], y));
    t[1] = VMIN3(t[1], VMAX(t[0], x), y);
    t[0] = VMIN3(t[0], x, y);
  }
  if (j < hi) {   // trailing single
    float4 p0 = pts[j];
    float d0 = fmaf(p0.z, m2z, fmaf(p0.y, m2y, fmaf(p0.x, m2x, p0.w)));
    if (j == selfpos) d0 = 3.0e38f;
    #pragma unroll
    for (int k = 15; k >= 1; --k)
      t[k] = VMIN(t[k], VMAX(t[k-1], d0));
    t[0] = VMIN(t[0], d0);
  }

  // merge the 8 part-lists: bitonic merges with partners ^8, ^16, ^32
  #pragma unroll
  for (int stepi = 0; stepi < 3; ++stepi) {
    const int step = 8 << stepi;
    float o_[16], m[16];
    #pragma unroll
    for (int i = 0; i < 16; ++i) o_[i] = __shfl(t[i], lane ^ step);
    #pragma unroll
    for (int i = 0; i < 16; ++i) m[i] = VMIN(t[i], o_[15 - i]);
    #define CE(i,jj) { float a_ = VMIN(m[i], m[jj]); float b_ = VMAX(m[i], m[jj]); m[i] = a_; m[jj] = b_; }
    CE(0,8) CE(1,9) CE(2,10) CE(3,11) CE(4,12) CE(5,13) CE(6,14) CE(7,15)
    CE(0,4) CE(1,5) CE(2,6)  CE(3,7)  CE(8,12) CE(9,13) CE(10,14) CE(11,15)
    CE(0,2) CE(1,3) CE(4,6)  CE(5,7)  CE(8,10) CE(9,11) CE(12,14) CE(13,15)
    CE(0,1) CE(2,3) CE(4,5)  CE(6,7)  CE(8,9)  CE(10,11) CE(12,13) CE(14,15)
    #undef CE
    #pragma unroll
    for (int i = 0; i < 16; ++i) t[i] = m[i];
  }

  if (part == 0) {
    int mq = read_mask(mask, mbase + qlocal, is8);
    float res[16];
    #pragma unroll
    for (int i = 0; i < 16; ++i) {
      float v = t[i];
      float d = (v > 1.0e37f) ? 24.0f : sqrtf(fmaxf(v + Q, 1e-12f)); // pad inf -> MAX_DIST
      res[i] = mq ? d : -1.0f;   // -1 sentinel => output row forced to zero
    }
    float4* dst = (float4*)(dists + (size_t)(mbase + qlocal) * KTOP);
    float4 o0, o1, o2, o3;
    o0.x=res[0];  o0.y=res[1];  o0.z=res[2];  o0.w=res[3];
    o1.x=res[4];  o1.y=res[5];  o1.z=res[6];  o1.w=res[7];
    o2.x=res[8];  o2.y=res[9];  o2.z=res[10]; o2.w=res[11];
    o3.x=res[12]; o3.y=res[13]; o3.z=res[14]; o3.w=res[15];
    dst[0]=o0; dst[1]=o1; dst[2]=o2; dst[3]=o3;
  }
}

// ---------------- kernel 2: fused RBF + projection (bf16 MFMA) ----------------
// grid: (2 n-blocks, QTOT/256 m-blocks) x 256 threads (4 waves).
// Wave owns 32 cols (2 W-frag sets as the MFMA *A* operand, 128 VGPR).
// rbf frags are the B operand -> each lane's 4 acc regs are 4 consecutive
// output COLUMNS of one row -> coalesced dwordx4 stores.
constexpr double SPd = 24.0 / 31.0;
constexpr double SP2d = SPd * SPd;
constexpr float ALPHA = (float)(-(SP2d / (SP2d + 1e-8)) * 1.4426950408889634);
constexpr float INV_SP = (float)(1.0 / SPd);

__device__ __forceinline__ void gen_tile(u32x4 (*Abuf)[1040], int row0, int s,
                                         float d0, float d1) {
  float dd0 = (d0 < 0.f) ? 1.0e9f : d0;   // sentinel -> rbf == 0
  float dd1 = (d1 < 0.f) ? 1.0e9f : d1;
  #pragma unroll
  for (int i = 0; i < 2; ++i) {
    float d = i ? dd1 : dd0;
    float u = d * INV_SP;
    float C1 = (-2.0f * ALPHA) * u;
    float C0 = ALPHA * u * u;
    #pragma unroll
    for (int c8 = 0; c8 < 4; ++c8) {
      u32x4 ch;
      #pragma unroll
      for (int q = 0; q < 4; ++q) {
        const int j0 = c8 * 8 + q * 2;
        float e0 = EXP2(fmaf(C1, (float)j0,       C0) + ALPHA * (float)(j0 * j0));
        float e1 = EXP2(fmaf(C1, (float)(j0 + 1), C0) + ALPHA * (float)((j0 + 1) * (j0 + 1)));
        ch[q] = pack2(e0, e1);
      }
      Abuf[i][s * 65 + c8 * 16 + row0] = ch;
    }
  }
}

__global__ __launch_bounds__(256, 2) void rbf_gemm_kernel(
    const float* __restrict__ dists, const float* __restrict__ W,
    float* __restrict__ out)
{
  __shared__ u32x4 A_sh[2][2][1040];   // [buf][row-half][s*65 + fragslot]

  const int tid = threadIdx.x;
  const int lane = tid & 63;
  const int wv = tid >> 6;
  const int c0 = blockIdx.x * 128 + wv * 32 + (lane & 15);
  const int ksub = (lane >> 4) * 8;

  // preload W fragments for 2 col-sets (used as MFMA A operand; m = W col)
  s16x8 bf0[16], bf1[16];
  const float* wr0 = W + (size_t)c0 * FDIM;
  const float* wr1 = wr0 + (size_t)16 * FDIM;
  #pragma unroll
  for (int s = 0; s < 16; ++s) {
    const float4* p0 = (const float4*)(wr0 + s * 32 + ksub);
    const float4* p1 = (const float4*)(wr1 + s * 32 + ksub);
    float4 a = p0[0], b = p0[1], c = p1[0], d = p1[1];
    u32x4 u0, u1;
    u0[0] = pack2(a.x, a.y); u0[1] = pack2(a.z, a.w);
    u0[2] = pack2(b.x, b.y); u0[3] = pack2(b.z, b.w);
    u1[0] = pack2(c.x, c.y); u1[1] = pack2(c.z, c.w);
    u1[2] = pack2(d.x, d.y); u1[3] = pack2(d.z, d.w);
    __builtin_memcpy(&bf0[s], &u0, sizeof(u0));
    __builtin_memcpy(&bf1[s], &u1, sizeof(u1));
  }

  const int row0 = tid >> 4;       // gen cell: row (and row+16), slot
  const int sgen = tid & 15;
  const int qbase0 = blockIdx.y * (32 * TTILES);
  const size_t dbase = (size_t)qbase0 * KTOP;

  float p0 = dists[dbase + tid];
  float p1 = dists[dbase + 256 + tid];
  gen_tile(A_sh[0], row0, sgen, p0, p1);

  for (int t = 0; t < TTILES; ++t) {
    float n0 = 0.f, n1 = 0.f;
    if (t + 1 < TTILES) {
      n0 = dists[dbase + (size_t)(t + 1) * 512 + tid];
      n1 = dists[dbase + (size_t)(t + 1) * 512 + 256 + tid];
    }
    __syncthreads();
    if (t + 1 < TTILES) gen_tile(A_sh[(t + 1) & 1], row0, sgen, n0, n1);

    const int buf = t & 1;
    f32x4 acc00 = {0.f,0.f,0.f,0.f}, acc01 = {0.f,0.f,0.f,0.f};
    f32x4 acc10 = {0.f,0.f,0.f,0.f}, acc11 = {0.f,0.f,0.f,0.f};
    #pragma unroll
    for (int s = 0; s < 16; ++s) {
      s16x8 a0, a1;
      u32x4 ra0 = A_sh[buf][0][s * 65 + lane];
      u32x4 ra1 = A_sh[buf][1][s * 65 + lane];
      __builtin_memcpy(&a0, &ra0, sizeof(ra0));
      __builtin_memcpy(&a1, &ra1, sizeof(ra1));
      // W as A (m = out col), rbf as B (n = out row)
      acc00 = __builtin_amdgcn_mfma_f32_16x16x32_bf16(bf0[s], a0, acc00, 0, 0, 0);
      acc01 = __builtin_amdgcn_mfma_f32_16x16x32_bf16(bf1[s], a0, acc01, 0, 0, 0);
      acc10 = __builtin_amdgcn_mfma_f32_16x16x32_bf16(bf0[s], a1, acc10, 0, 0, 0);
      acc11 = __builtin_amdgcn_mfma_f32_16x16x32_bf16(bf1[s], a1, acc11, 0, 0, 0);
    }

    const int qbase = qbase0 + t * 32;
    const int qr = lane & 15;                       // out row (n)
    const int colb = blockIdx.x * 128 + wv * 32 + (lane >> 4) * 4;  // out col base (m)
    float* o0 = out + (size_t)(qbase + qr) * ODIM + colb;        // rows half 0
    float* o1 = out + (size_t)(qbase + 16 + qr) * ODIM + colb;   // rows half 1
    __builtin_nontemporal_store(acc00, (f32x4*)o0);
    __builtin_nontemporal_store(acc01, (f32x4*)(o0 + 16));
    __builtin_nontemporal_store(acc10, (f32x4*)o1);
    __builtin_nontemporal_store(acc11, (f32x4*)(o1 + 16));
  }
}

extern "C" void kernel_launch(void* const* d_in, const int* in_sizes, int n_in,
                              void* d_out, int out_size, void* d_ws, size_t ws_size,
                              hipStream_t stream) {
  const float* coords = (const float*)d_in[0];
  const void* mask = d_in[1];
  const float* W = (const float*)d_in[2];
  float* out = (float*)d_out;
  float* dists = (float*)d_ws;   // QTOT * 16 fp32 = 4 MB scratch

  hipLaunchKernelGGL(topk_kernel, dim3(QTOT / 64), dim3(512), 0, stream,
                     coords, mask, dists);
  hipLaunchKernelGGL(rbf_gemm_kernel, dim3(2, QTOT / (32 * TTILES)), dim3(256), 0, stream,
                     dists, W, out);
}